// Round 1
// 1488.511 us; speedup vs baseline: 1.2079x; 1.2079x over previous
//
#include <hip/hip_runtime.h>

// ---------------------------------------------------------------------------
// MoE Autoencoder, MI355X (gfx950). DTYPE-ADAPTIVE (f32 or bf16 inputs).
// R1 changes vs previous best (1798us):
//  - enc_gemm UNFUSED from gating: counters showed 400us with MfmaUtil=7%
//    (28us of MFMA work) -- the shuffle+atomicAdd gating epilogue was ~370us.
//    Gating now a dedicated gate_from_h kernel (one 64MB re-read of H).
//  - Expert phase: one merged launch (grid.z=expert) + batched weight
//    transposes into wTall (needs +80MB ws; host falls back to the serial
//    per-expert path if ws_size is too small -- no correctness risk).
// ---------------------------------------------------------------------------

#define N_TOK 16384
#define IN_DIM 1024
#define HID 2048
#define NEXP 8
#define TAU 8.0e-3f

typedef __bf16 bf16_t;
typedef __bf16 bf16x8 __attribute__((ext_vector_type(8)));
typedef __bf16 bf16x4v __attribute__((ext_vector_type(4)));
typedef float f32x4 __attribute__((ext_vector_type(4)));
typedef unsigned short ushort_t;

#define CLAMP1E4(v) fmaxf(fminf((v), 1.0e4f), -1.0e4f)

#define ASYNC16(gp, lp)                                                        \
  __builtin_amdgcn_global_load_lds(                                            \
      (const __attribute__((address_space(1))) void*)(gp),                     \
      (__attribute__((address_space(3))) void*)(lp), 16, 0, 0)

static __device__ inline ushort_t b2u(bf16_t v) {
  union { bf16_t b; ushort_t u; } x; x.b = v; return x.u;
}

// ---------------------------------------------------------------------------
__global__ __launch_bounds__(256) void fill_bf16(bf16_t* __restrict__ p,
                                                 float v, int n) {
  const int i = blockIdx.x * 256 + threadIdx.x;
  if (i < n) p[i] = (bf16_t)v;
}

// ---------------------------------------------------------------------------
// flag=1  <=>  raw data is f32 (reading it as bf16 yields wild exponents)
// ---------------------------------------------------------------------------
__global__ __launch_bounds__(256) void detect_dtype(
    const ushort_t* __restrict__ xr, int* __restrict__ flag) {
  __shared__ int s_bad;
  if (threadIdx.x == 0) s_bad = 0;
  __syncthreads();
  int bad = 0;
  for (int i = threadIdx.x; i < 4096; i += 256) {
    const int e = (xr[i] >> 7) & 0xFF;
    if (e >= 0xC0) bad = 1;  // |v| >= 2^65: impossible for real bf16 data
  }
  if (__any(bad) && (threadIdx.x & 63) == 0) atomicOr(&s_bad, 1);
  __syncthreads();
  if (threadIdx.x == 0) *flag = s_bad;
}

// ---------------------------------------------------------------------------
__global__ __launch_bounds__(256) void cvt_to_bf16(
    const void* __restrict__ src, bf16_t* __restrict__ dst, int n,
    const int* __restrict__ flagp) {
  const int f = *flagp;
  const int i = blockIdx.x * 256 + threadIdx.x;
  if (i >= n) return;
  dst[i] = f ? (bf16_t)((const float*)src)[i] : ((const bf16_t*)src)[i];
}

// vectorized x4 variant for the big x conversion
__global__ __launch_bounds__(256) void cvt_to_bf16_x4(
    const void* __restrict__ src, bf16_t* __restrict__ dst, int n4,
    const int* __restrict__ flagp) {
  const int f = *flagp;
  const int i = blockIdx.x * 256 + threadIdx.x;
  if (i >= n4) return;
  bf16x4v o;
  if (f) {
    const f32x4 v = ((const f32x4*)src)[i];
    o[0] = (bf16_t)v[0]; o[1] = (bf16_t)v[1];
    o[2] = (bf16_t)v[2]; o[3] = (bf16_t)v[3];
  } else {
    o = ((const bf16x4v*)src)[i];
  }
  ((bf16x4v*)dst)[i] = o;
}

__global__ __launch_bounds__(256) void cvt_to_f32(
    const void* __restrict__ src, float* __restrict__ dst, int n,
    const int* __restrict__ flagp) {
  const int f = *flagp;
  const int i = blockIdx.x * 256 + threadIdx.x;
  if (i >= n) return;
  dst[i] = f ? ((const float*)src)[i] : (float)((const bf16_t*)src)[i];
}

// ---------------------------------------------------------------------------
// transpose + convert: src[R][C] (f32 or bf16 per flag) -> dst[C][R] bf16.
// elem_off: element offset into src. z strides allow batched (grid.z) use.
// ---------------------------------------------------------------------------
__global__ __launch_bounds__(256) void transpose_cvt(
    const void* __restrict__ src0, ushort_t* __restrict__ dst, int R, int C,
    size_t elem_off, const int* __restrict__ flagp, size_t src_zstride,
    size_t dst_zstride) {
  __shared__ ushort_t t[32][33];
  const int f = *flagp;
  const size_t eoff = elem_off + (size_t)blockIdx.z * src_zstride;
  dst += (size_t)blockIdx.z * dst_zstride;
  const int c0 = blockIdx.x * 32, r0 = blockIdx.y * 32;
  const int tx = threadIdx.x, ty = threadIdx.y;
  if (f) {
    const float* s = (const float*)src0 + eoff;
#pragma unroll
    for (int i = 0; i < 4; ++i)
      t[ty + i * 8][tx] =
          b2u((bf16_t)s[(size_t)(r0 + ty + i * 8) * C + c0 + tx]);
  } else {
    const ushort_t* s = (const ushort_t*)src0 + eoff;
#pragma unroll
    for (int i = 0; i < 4; ++i)
      t[ty + i * 8][tx] = s[(size_t)(r0 + ty + i * 8) * C + c0 + tx];
  }
  __syncthreads();
#pragma unroll
  for (int i = 0; i < 4; ++i)
    dst[(size_t)(c0 + ty + i * 8) * R + r0 + tx] = t[tx][ty + i * 8];
}

// ---------------------------------------------------------------------------
// enc: h = relu(x @ enc_W + b) (bf16). Pure GEMM + bias + relu (gating moved
// to gate_from_h: the fused epilogue was 370us of shuffle/atomic stall).
// ---------------------------------------------------------------------------
__global__ __launch_bounds__(256) void enc_gemm(
    const bf16_t* __restrict__ A, const bf16_t* __restrict__ Bt,
    const float* __restrict__ bias, bf16_t* __restrict__ H) {
  __shared__ bf16_t As[128 * 32];
  __shared__ bf16_t Bs[128 * 32];

  const int tid = threadIdx.x, lane = tid & 63, w = tid >> 6;
  const int wr = w >> 1, wc = w & 1, quad = lane >> 4, l16 = lane & 15;
  const int m0 = blockIdx.x * 128, n0 = blockIdx.y * 128;
  const char* Ab = (const char*)A;
  const char* Bb = (const char*)Bt;
  const size_t lda = (size_t)IN_DIM * 2;

  const f32x4 fz = {0.f, 0.f, 0.f, 0.f};
  f32x4 acc[4][4];
#pragma unroll
  for (int i = 0; i < 4; ++i)
#pragma unroll
    for (int j = 0; j < 4; ++j) acc[i][j] = fz;

  size_t aoff[2], boff[2];
  int cb[2];
#pragma unroll
  for (int c = 0; c < 2; ++c) {
    cb[c] = (w * 2 + c) * 1024;
    const int o = cb[c] + lane * 16;
    const int row = o >> 6, kb = o & 63;
    aoff[c] = (size_t)(m0 + row) * lda + kb;
    boff[c] = (size_t)(n0 + row) * lda + kb;
  }

  for (int kt = 0; kt < IN_DIM / 32; ++kt) {
    __syncthreads();
#pragma unroll
    for (int c = 0; c < 2; ++c) {
      ASYNC16(Ab + aoff[c] + (size_t)kt * 64, (char*)As + cb[c]);
      ASYNC16(Bb + boff[c] + (size_t)kt * 64, (char*)Bs + cb[c]);
    }
    __syncthreads();

    bf16x8 af[4], bfr[4];
#pragma unroll
    for (int i = 0; i < 4; ++i)
      af[i] = *(const bf16x8*)&As[(wr * 64 + i * 16 + l16) * 32 + quad * 8];
#pragma unroll
    for (int j = 0; j < 4; ++j)
      bfr[j] = *(const bf16x8*)&Bs[(wc * 64 + j * 16 + l16) * 32 + quad * 8];
#pragma unroll
    for (int i = 0; i < 4; ++i)
#pragma unroll
      for (int j = 0; j < 4; ++j)
        acc[i][j] = __builtin_amdgcn_mfma_f32_16x16x32_bf16(af[i], bfr[j],
                                                            acc[i][j], 0, 0, 0);
  }

  float bj[4];
  int colj[4];
#pragma unroll
  for (int j = 0; j < 4; ++j) {
    colj[j] = n0 + wc * 64 + j * 16 + l16;
    bj[j] = bias[colj[j]];
  }

#pragma unroll
  for (int i = 0; i < 4; ++i) {
#pragma unroll
    for (int r = 0; r < 4; ++r) {
      const int row = m0 + wr * 64 + i * 16 + quad * 4 + r;
#pragma unroll
      for (int j = 0; j < 4; ++j) {
        const float v = fminf(fmaxf(acc[i][j][r] + bj[j], 0.f), 1.0e4f);
        H[(size_t)row * HID + colj[j]] = (bf16_t)v;
      }
    }
  }
}

// ---------------------------------------------------------------------------
// gate_from_h: one wave per 4 rows. Reads H (bf16), computes the 8 gate
// logits + 2 coef logits per row with a full 64-lane butterfly reduce, then
// does the cheap softmax/argmax. Rows with top-2 gap < TAU go to f64 rescue.
// bf16-rounding of H perturbs logits by ~3e-4 << TAU, so argmax exactness is
// preserved via the rescue path.
// ---------------------------------------------------------------------------
__global__ __launch_bounds__(256) void gate_from_h(
    const bf16_t* __restrict__ H, const bf16_t* __restrict__ gW,
    const bf16_t* __restrict__ cW, const float* __restrict__ coefBf,
    float* __restrict__ s0g, float* __restrict__ s1g, float* __restrict__ c0g,
    int* __restrict__ eidx, int* __restrict__ ambig, int* __restrict__ acnt) {
  const int tid = threadIdx.x, lane = tid & 63, w = tid >> 6;
  const int r0 = blockIdx.x * 16 + w * 4;  // 4 waves * 4 rows per block

  float acc[4][10];
#pragma unroll
  for (int g = 0; g < 4; ++g)
#pragma unroll
    for (int o = 0; o < 10; ++o) acc[g][o] = 0.f;

#pragma unroll
  for (int it = 0; it < HID / 512; ++it) {  // 4 iterations
    const int h0 = it * 512 + lane * 8;
    bf16x8 hv[4];
#pragma unroll
    for (int g = 0; g < 4; ++g)
      hv[g] = *(const bf16x8*)(H + (size_t)(r0 + g) * HID + h0);
    const bf16_t* gp = gW + (size_t)h0 * 8;
    const bf16_t* cp = cW + (size_t)h0 * 2;
    bf16x8 cc0 = *(const bf16x8*)(cp);
    bf16x8 cc1 = *(const bf16x8*)(cp + 8);
#pragma unroll
    for (int k = 0; k < 8; ++k) {
      const bf16x8 gk = *(const bf16x8*)(gp + k * 8);
      const float ck0 = (k < 4) ? (float)cc0[(k & 3) * 2]
                                : (float)cc1[(k & 3) * 2];
      const float ck1 = (k < 4) ? (float)cc0[(k & 3) * 2 + 1]
                                : (float)cc1[(k & 3) * 2 + 1];
#pragma unroll
      for (int g = 0; g < 4; ++g) {
        const float v = (float)hv[g][k];
#pragma unroll
        for (int o = 0; o < 8; ++o) acc[g][o] += v * (float)gk[o];
        acc[g][8] += v * ck0;
        acc[g][9] += v * ck1;
      }
    }
  }

#pragma unroll
  for (int m = 1; m < 64; m <<= 1)
#pragma unroll
    for (int g = 0; g < 4; ++g)
#pragma unroll
      for (int o = 0; o < 10; ++o) acc[g][o] += __shfl_xor(acc[g][o], m);

  if (lane == 0) {
#pragma unroll
    for (int g = 0; g < 4; ++g) {
      const int r = r0 + g;
      float lv[8];
#pragma unroll
      for (int e = 0; e < 8; ++e) lv[e] = acc[g][e];
      float mx = lv[0];
      int idx = 0;
#pragma unroll
      for (int e = 1; e < 8; ++e)
        if (lv[e] > mx) { mx = lv[e]; idx = e; }
      float s2 = -1.0e30f;
#pragma unroll
      for (int e = 0; e < 8; ++e)
        if (e != idx) s2 = fmaxf(s2, lv[e]);
      float s = 0.f;
#pragma unroll
      for (int e = 0; e < 8; ++e) s += expf(lv[e] - mx);
      const float gate = 1.f / s;
      const float c0 = acc[g][8] + coefBf[0], c1 = acc[g][9] + coefBf[1];
      const float cm = fmaxf(c0, c1);
      const float e0 = expf(c0 - cm), e1 = expf(c1 - cm);
      const float inv = 1.f / (e0 + e1);
      const float p0 = e0 * inv;
      c0g[r] = p0;
      s1g[r] = e1 * inv;
      s0g[r] = gate * p0;
      eidx[r] = idx;
      if (mx - s2 < TAU) {
        const int p = atomicAdd(acnt, 1);
        ambig[p] = r;
      }
    }
  }
}

// ---------------------------------------------------------------------------
// f64 rescue of ambiguous rows: recompute h + gate logits exactly from the
// RAW inputs (f32 or bf16 per flag); overwrite eidx / s0g.
// ---------------------------------------------------------------------------
__global__ __launch_bounds__(256) void rescue_rows(
    const void* __restrict__ xraw, const void* __restrict__ encWraw,
    const float* __restrict__ encBf, const void* __restrict__ gateWraw,
    const int* __restrict__ flagp, const int* __restrict__ ambig,
    const int* __restrict__ acnt, const float* __restrict__ c0g,
    float* __restrict__ s0g, int* __restrict__ eidx) {
  const int i = blockIdx.x;
  if (i >= *acnt) return;
  const int r = ambig[i];
  const int f = *flagp;
  const int tid = threadIdx.x;

  double hacc[8] = {0, 0, 0, 0, 0, 0, 0, 0};
  if (f) {
    const float* x = (const float*)xraw + (size_t)r * IN_DIM;
    const float* W = (const float*)encWraw;
    for (int k = 0; k < IN_DIM; ++k) {
      const double xv = (double)x[k];
      const float* Wr = W + (size_t)k * HID;
#pragma unroll
      for (int jj = 0; jj < 8; ++jj)
        hacc[jj] += xv * (double)Wr[tid + jj * 256];
    }
  } else {
    const bf16_t* x = (const bf16_t*)xraw + (size_t)r * IN_DIM;
    const bf16_t* W = (const bf16_t*)encWraw;
    for (int k = 0; k < IN_DIM; ++k) {
      const double xv = (double)(float)x[k];
      const bf16_t* Wr = W + (size_t)k * HID;
#pragma unroll
      for (int jj = 0; jj < 8; ++jj)
        hacc[jj] += xv * (double)(float)Wr[tid + jj * 256];
    }
  }

  double lg[8] = {0, 0, 0, 0, 0, 0, 0, 0};
#pragma unroll
  for (int jj = 0; jj < 8; ++jj) {
    const int j = tid + jj * 256;
    double h = hacc[jj] + (double)encBf[j];
    if (h > 0.0) {
      if (f) {
        const float* g = (const float*)gateWraw + (size_t)j * 8;
#pragma unroll
        for (int e = 0; e < 8; ++e) lg[e] += h * (double)g[e];
      } else {
        const bf16_t* g = (const bf16_t*)gateWraw + (size_t)j * 8;
#pragma unroll
        for (int e = 0; e < 8; ++e) lg[e] += h * (double)(float)g[e];
      }
    }
  }
#pragma unroll
  for (int m = 1; m < 64; m <<= 1)
#pragma unroll
    for (int e = 0; e < 8; ++e) lg[e] += __shfl_xor(lg[e], m);

  __shared__ double red[4][8];
  const int w = tid >> 6, lane = tid & 63;
  if (lane == 0)
#pragma unroll
    for (int e = 0; e < 8; ++e) red[w][e] = lg[e];
  __syncthreads();
  if (tid == 0) {
    double t[8];
#pragma unroll
    for (int e = 0; e < 8; ++e)
      t[e] = red[0][e] + red[1][e] + red[2][e] + red[3][e];
    double m = t[0];
    int idx = 0;
#pragma unroll
    for (int e = 1; e < 8; ++e)
      if (t[e] > m) { m = t[e]; idx = e; }
    double s = 0.0;
#pragma unroll
    for (int e = 0; e < 8; ++e) s += exp(t[e] - m);
    s0g[r] = (float)((1.0 / s) * (double)c0g[r]);
    eidx[r] = idx;
  }
}

// ---------------------------------------------------------------------------
__global__ __launch_bounds__(256) void bucket_rows(
    const int* __restrict__ eidx, int* __restrict__ cnt,
    int* __restrict__ perm) {
  const int r = blockIdx.x * 256 + threadIdx.x;
  const int e = eidx[r];
  const int pos = atomicAdd(&cnt[e], 1);
  perm[(size_t)e * N_TOK + pos] = r;
}

// ---------------------------------------------------------------------------
// expert GEMM: mid[grow] = s0 * (h[grow] @ We + be).
// eArg >= 0: serial mode (one expert per launch, wstride=0 reuses wT).
// eArg <  0: merged mode, expert = blockIdx.z, weights at wTbase+e*wstride.
// ---------------------------------------------------------------------------
__global__ __launch_bounds__(256) void expert_gemm(
    const bf16_t* __restrict__ H, const bf16_t* __restrict__ wTbase,
    size_t wstride, const float* __restrict__ expBf,
    const int* __restrict__ perm, const int* __restrict__ cnt, int eArg,
    const float* __restrict__ s0g, bf16_t* __restrict__ mid) {
  __shared__ bf16_t As[128 * 32];
  __shared__ bf16_t Bs[128 * 32];
  __shared__ int rows_s[128];
  __shared__ float s0_s[128];

  const int e = (eArg >= 0) ? eArg : (int)blockIdx.z;
  const bf16_t* wTe = wTbase + (size_t)e * wstride;
  const float* eBe = expBf + (size_t)e * HID;
  const int* permE = perm + (size_t)e * N_TOK;

  const int cnte = cnt[e];
  const int lt = blockIdx.x;
  if (lt * 128 >= cnte) return;
  int nrows = cnte - lt * 128;
  if (nrows > 128) nrows = 128;

  const int tid = threadIdx.x, lane = tid & 63, w = tid >> 6;
  const int wr = w >> 1, wc = w & 1, quad = lane >> 4, l16 = lane & 15;

  if (tid < 128) {
    int grow = -1;
    float a0 = 0.f;
    if (tid < nrows) {
      grow = permE[lt * 128 + tid];
      a0 = s0g[grow];
    }
    rows_s[tid] = grow;
    s0_s[tid] = a0;
  }
  __syncthreads();

  const int n0 = blockIdx.y * 128;
  const char* Hb = (const char*)H;
  const char* Wb = (const char*)wTe;

  size_t aoff[2], boff[2];
  int cb[2];
#pragma unroll
  for (int c = 0; c < 2; ++c) {
    cb[c] = (w * 2 + c) * 1024;
    const int o = cb[c] + lane * 16;
    const int row = o >> 6, kb = o & 63;
    int gr = rows_s[row];
    if (gr < 0) gr = 0;
    aoff[c] = (size_t)gr * (HID * 2) + kb;
    boff[c] = (size_t)(n0 + row) * (HID * 2) + kb;
  }

  const f32x4 fz = {0.f, 0.f, 0.f, 0.f};
  f32x4 acc[4][4];
#pragma unroll
  for (int i = 0; i < 4; ++i)
#pragma unroll
    for (int j = 0; j < 4; ++j) acc[i][j] = fz;

  for (int kt = 0; kt < HID / 32; ++kt) {
    __syncthreads();
#pragma unroll
    for (int c = 0; c < 2; ++c) {
      ASYNC16(Hb + aoff[c] + (size_t)kt * 64, (char*)As + cb[c]);
      ASYNC16(Wb + boff[c] + (size_t)kt * 64, (char*)Bs + cb[c]);
    }
    __syncthreads();

    bf16x8 af[4], bfr[4];
#pragma unroll
    for (int i = 0; i < 4; ++i)
      af[i] = *(const bf16x8*)&As[(wr * 64 + i * 16 + l16) * 32 + quad * 8];
#pragma unroll
    for (int j = 0; j < 4; ++j)
      bfr[j] = *(const bf16x8*)&Bs[(wc * 64 + j * 16 + l16) * 32 + quad * 8];
#pragma unroll
    for (int i = 0; i < 4; ++i)
#pragma unroll
      for (int j = 0; j < 4; ++j)
        acc[i][j] = __builtin_amdgcn_mfma_f32_16x16x32_bf16(af[i], bfr[j],
                                                            acc[i][j], 0, 0, 0);
  }

  float beb[4];
  int colj[4];
#pragma unroll
  for (int j = 0; j < 4; ++j) {
    colj[j] = n0 + wc * 64 + j * 16 + l16;
    beb[j] = eBe[colj[j]];
  }
#pragma unroll
  for (int i = 0; i < 4; ++i) {
#pragma unroll
    for (int r = 0; r < 4; ++r) {
      const int lr = wr * 64 + i * 16 + quad * 4 + r;
      const int grow = rows_s[lr];
      if (grow < 0) continue;
      const float s0 = s0_s[lr];
#pragma unroll
      for (int j = 0; j < 4; ++j) {
        const float v = CLAMP1E4(s0 * (acc[i][j][r] + beb[j]));
        mid[(size_t)grow * HID + colj[j]] = (bf16_t)v;
      }
    }
  }
}

// ---------------------------------------------------------------------------
// res: mid[row] += s1[row] * (h[row] @ Wr + rb)
// ---------------------------------------------------------------------------
__global__ __launch_bounds__(256) void res_gemm(
    const bf16_t* __restrict__ H, const bf16_t* __restrict__ Bt,
    const float* __restrict__ rB, const float* __restrict__ s1g,
    bf16_t* __restrict__ mid) {
  __shared__ bf16_t As[128 * 32];
  __shared__ bf16_t Bs[128 * 32];

  const int tid = threadIdx.x, lane = tid & 63, w = tid >> 6;
  const int wr = w >> 1, wc = w & 1, quad = lane >> 4, l16 = lane & 15;
  const int m0 = blockIdx.x * 128, n0 = blockIdx.y * 128;
  const char* Ab = (const char*)H;
  const char* Bb = (const char*)Bt;

  size_t aoff[2], boff[2];
  int cb[2];
#pragma unroll
  for (int c = 0; c < 2; ++c) {
    cb[c] = (w * 2 + c) * 1024;
    const int o = cb[c] + lane * 16;
    const int row = o >> 6, kb = o & 63;
    aoff[c] = (size_t)(m0 + row) * (HID * 2) + kb;
    boff[c] = (size_t)(n0 + row) * (HID * 2) + kb;
  }

  const f32x4 fz = {0.f, 0.f, 0.f, 0.f};
  f32x4 acc[4][4];
#pragma unroll
  for (int i = 0; i < 4; ++i)
#pragma unroll
    for (int j = 0; j < 4; ++j) acc[i][j] = fz;

  for (int kt = 0; kt < HID / 32; ++kt) {
    __syncthreads();
#pragma unroll
    for (int c = 0; c < 2; ++c) {
      ASYNC16(Ab + aoff[c] + (size_t)kt * 64, (char*)As + cb[c]);
      ASYNC16(Bb + boff[c] + (size_t)kt * 64, (char*)Bs + cb[c]);
    }
    __syncthreads();

    bf16x8 af[4], bfr[4];
#pragma unroll
    for (int i = 0; i < 4; ++i)
      af[i] = *(const bf16x8*)&As[(wr * 64 + i * 16 + l16) * 32 + quad * 8];
#pragma unroll
    for (int j = 0; j < 4; ++j)
      bfr[j] = *(const bf16x8*)&Bs[(wc * 64 + j * 16 + l16) * 32 + quad * 8];
#pragma unroll
    for (int i = 0; i < 4; ++i)
#pragma unroll
      for (int j = 0; j < 4; ++j)
        acc[i][j] = __builtin_amdgcn_mfma_f32_16x16x32_bf16(af[i], bfr[j],
                                                            acc[i][j], 0, 0, 0);
  }

  float rbb[4];
  int colj[4];
#pragma unroll
  for (int j = 0; j < 4; ++j) {
    colj[j] = n0 + wc * 64 + j * 16 + l16;
    rbb[j] = rB[colj[j]];
  }
#pragma unroll
  for (int i = 0; i < 4; ++i) {
#pragma unroll
    for (int r = 0; r < 4; ++r) {
      const int row = m0 + wr * 64 + i * 16 + quad * 4 + r;
      const float s1 = s1g[row];
#pragma unroll
      for (int j = 0; j < 4; ++j) {
        const size_t ix = (size_t)row * HID + colj[j];
        const float v =
            CLAMP1E4(s1 * (acc[i][j][r] + rbb[j]) + (float)mid[ix]);
        mid[ix] = (bf16_t)v;
      }
    }
  }
}

// ---------------------------------------------------------------------------
// dec: out = mid @ dec_W + dec_b; output dtype per flag (f32 or bf16).
// ---------------------------------------------------------------------------
__global__ __launch_bounds__(256) void dec_gemm(
    const bf16_t* __restrict__ A, const bf16_t* __restrict__ Bt,
    const float* __restrict__ bias, void* __restrict__ C,
    const int* __restrict__ flagp) {
  __shared__ bf16_t As[128 * 32];
  __shared__ bf16_t Bs[128 * 32];

  const int fl = *flagp;
  const int tid = threadIdx.x, lane = tid & 63, w = tid >> 6;
  const int wr = w >> 1, wc = w & 1, quad = lane >> 4, l16 = lane & 15;
  const int m0 = blockIdx.x * 128, n0 = blockIdx.y * 128;
  const char* Ab = (const char*)A;
  const char* Bb = (const char*)Bt;

  size_t aoff[2], boff[2];
  int cb[2];
#pragma unroll
  for (int c = 0; c < 2; ++c) {
    cb[c] = (w * 2 + c) * 1024;
    const int o = cb[c] + lane * 16;
    const int row = o >> 6, kb = o & 63;
    aoff[c] = (size_t)(m0 + row) * (HID * 2) + kb;
    boff[c] = (size_t)(n0 + row) * (HID * 2) + kb;
  }

  const f32x4 fz = {0.f, 0.f, 0.f, 0.f};
  f32x4 acc[4][4];
#pragma unroll
  for (int i = 0; i < 4; ++i)
#pragma unroll
    for (int j = 0; j < 4; ++j) acc[i][j] = fz;

  for (int kt = 0; kt < HID / 32; ++kt) {
    __syncthreads();
#pragma unroll
    for (int c = 0; c < 2; ++c) {
      ASYNC16(Ab + aoff[c] + (size_t)kt * 64, (char*)As + cb[c]);
      ASYNC16(Bb + boff[c] + (size_t)kt * 64, (char*)Bs + cb[c]);
    }
    __syncthreads();

    bf16x8 af[4], bfr[4];
#pragma unroll
    for (int i = 0; i < 4; ++i)
      af[i] = *(const bf16x8*)&As[(wr * 64 + i * 16 + l16) * 32 + quad * 8];
#pragma unroll
    for (int j = 0; j < 4; ++j)
      bfr[j] = *(const bf16x8*)&Bs[(wc * 64 + j * 16 + l16) * 32 + quad * 8];
#pragma unroll
    for (int i = 0; i < 4; ++i)
#pragma unroll
      for (int j = 0; j < 4; ++j)
        acc[i][j] = __builtin_amdgcn_mfma_f32_16x16x32_bf16(af[i], bfr[j],
                                                            acc[i][j], 0, 0, 0);
  }

  float bb[4];
  int colj[4];
#pragma unroll
  for (int j = 0; j < 4; ++j) {
    colj[j] = n0 + wc * 64 + j * 16 + l16;
    bb[j] = bias[colj[j]];
  }
#pragma unroll
  for (int i = 0; i < 4; ++i) {
#pragma unroll
    for (int r = 0; r < 4; ++r) {
      const int row = m0 + wr * 64 + i * 16 + quad * 4 + r;
#pragma unroll
      for (int j = 0; j < 4; ++j) {
        const float v = CLAMP1E4(acc[i][j][r] + bb[j]);
        const size_t ix = (size_t)row * IN_DIM + colj[j];
        if (fl)
          ((float*)C)[ix] = v;
        else
          ((bf16_t*)C)[ix] = (bf16_t)v;
      }
    }
  }
}

// ---------------------------------------------------------------------------
extern "C" void kernel_launch(void* const* d_in, const int* in_sizes, int n_in,
                              void* d_out, int out_size, void* d_ws,
                              size_t ws_size, hipStream_t stream) {
  (void)in_sizes; (void)n_in;

  const void* x     = d_in[0];
  const void* encW  = d_in[1];
  const void* encB  = d_in[2];
  const void* gateW = d_in[3];
  const void* expW  = d_in[4];
  const void* expB  = d_in[5];
  const void* resW  = d_in[6];
  const void* resB  = d_in[7];
  const void* coefW = d_in[8];
  const void* coefB = d_in[9];
  const void* decW  = d_in[10];
  const void* decB  = d_in[11];

  // --- workspace layout: ~137MB base, +80MB wTall if available ---
  char* ws = (char*)d_ws;
  size_t o = 0;
  int*    flag  = (int*)(ws + o);    o += 256;
  int*    cnt   = (int*)(ws + o);    o += 256;   // cnt[0..7]; acnt at cnt[8]
  int*    acnt  = cnt + 8;
  float*  s0g   = (float*)(ws + o);  o += (size_t)N_TOK * 4;
  float*  s1g   = (float*)(ws + o);  o += (size_t)N_TOK * 4;
  float*  c0g   = (float*)(ws + o);  o += (size_t)N_TOK * 4;
  int*    eidx  = (int*)(ws + o);    o += (size_t)N_TOK * 4;
  int*    ambig = (int*)(ws + o);    o += (size_t)N_TOK * 4;
  int*    perm  = (int*)(ws + o);    o += (size_t)NEXP * N_TOK * 4;
  float*  encBf = (float*)(ws + o);  o += HID * 4;
  float*  expBf = (float*)(ws + o);  o += (size_t)NEXP * HID * 4;
  float*  resBf = (float*)(ws + o);  o += HID * 4;
  float*  decBf = (float*)(ws + o);  o += IN_DIM * 4;
  float*  coefBf= (float*)(ws + o);  o += 256;
  bf16_t* gWb   = (bf16_t*)(ws + o); o += (size_t)HID * 8 * 2;
  bf16_t* cWb   = (bf16_t*)(ws + o); o += (size_t)HID * 2 * 2;
  o = (o + 255) & ~(size_t)255;
  bf16_t* hbuf  = (bf16_t*)(ws + o); o += (size_t)N_TOK * HID * 2;   // 64 MB
  bf16_t* mid   = (bf16_t*)(ws + o); o += (size_t)N_TOK * HID * 2;   // 64 MB
  bf16_t* wT    = (bf16_t*)(ws + o); o += (size_t)HID * HID * 2;     // 8 MB
  const size_t needed_small = o;
  const size_t S = (size_t)HID * HID;  // elements per wTall slot
  bf16_t* wTall = (bf16_t*)(ws + o);   // slots 0..7 experts, 8 res, 9 dec
  const size_t needed_big = o + 10 * S * 2;                          // +80 MB
  bf16_t* xbf = mid;  // alias: xbf dead before expert_gemm writes mid

  if (ws_size < needed_small) {
    const float v = (float)(ws_size >> 20);  // report budget in MB
    fill_bf16<<<dim3((out_size + 255) / 256), 256, 0, stream>>>(
        (bf16_t*)d_out, v, out_size);
    return;
  }
  const bool big = ws_size >= needed_big;

  detect_dtype<<<1, 256, 0, stream>>>((const ushort_t*)x, flag);
  hipMemsetAsync(cnt, 0, 256, stream);

  // --- normalize inputs ---
  cvt_to_bf16_x4<<<dim3(N_TOK * IN_DIM / 4 / 256), 256, 0, stream>>>(
      x, xbf, N_TOK * IN_DIM / 4, flag);
  cvt_to_f32<<<dim3(HID / 256), 256, 0, stream>>>(encB, encBf, HID, flag);
  cvt_to_f32<<<dim3(NEXP * HID / 256), 256, 0, stream>>>(expB, expBf,
                                                         NEXP * HID, flag);
  cvt_to_f32<<<dim3(HID / 256), 256, 0, stream>>>(resB, resBf, HID, flag);
  cvt_to_f32<<<dim3(IN_DIM / 256), 256, 0, stream>>>(decB, decBf, IN_DIM, flag);
  cvt_to_f32<<<1, 256, 0, stream>>>(coefB, coefBf, 2, flag);
  cvt_to_bf16<<<dim3(HID * 8 / 256), 256, 0, stream>>>(gateW, gWb, HID * 8,
                                                       flag);
  cvt_to_bf16<<<dim3(HID * 2 / 256), 256, 0, stream>>>(coefW, cWb, HID * 2,
                                                       flag);

  const dim3 tb(32, 8, 1);

  // --- weight prep (hoisted off the critical path where possible) ---
  transpose_cvt<<<dim3(HID / 32, IN_DIM / 32, 1), tb, 0, stream>>>(
      encW, (ushort_t*)wT, IN_DIM, HID, 0, flag, 0, 0);
  if (big) {
    transpose_cvt<<<dim3(HID / 32, HID / 32, NEXP), tb, 0, stream>>>(
        expW, (ushort_t*)wTall, HID, HID, 0, flag, S, S);
    transpose_cvt<<<dim3(HID / 32, HID / 32, 1), tb, 0, stream>>>(
        resW, (ushort_t*)(wTall + 8 * S), HID, HID, 0, flag, 0, 0);
    transpose_cvt<<<dim3(IN_DIM / 32, HID / 32, 1), tb, 0, stream>>>(
        decW, (ushort_t*)(wTall + 9 * S), HID, IN_DIM, 0, flag, 0, 0);
  }

  // --- enc + gating ---
  enc_gemm<<<dim3(N_TOK / 128, HID / 128), 256, 0, stream>>>(xbf, wT, encBf,
                                                             hbuf);
  gate_from_h<<<dim3(N_TOK / 16), 256, 0, stream>>>(
      hbuf, gWb, cWb, coefBf, s0g, s1g, c0g, eidx, ambig, acnt);
  rescue_rows<<<dim3(1024), 256, 0, stream>>>(x, encW, encBf, gateW, flag,
                                              ambig, acnt, c0g, s0g, eidx);
  bucket_rows<<<dim3(N_TOK / 256), 256, 0, stream>>>(eidx, cnt, perm);

  if (big) {
    // --- all 8 experts in ONE launch (grid.z = expert) ---
    expert_gemm<<<dim3(N_TOK / 128, HID / 128, NEXP), 256, 0, stream>>>(
        hbuf, wTall, S, expBf, perm, cnt, -1, s0g, mid);
    res_gemm<<<dim3(N_TOK / 128, HID / 128), 256, 0, stream>>>(
        hbuf, wTall + 8 * S, resBf, s1g, mid);
    dec_gemm<<<dim3(N_TOK / 128, IN_DIM / 128), 256, 0, stream>>>(
        mid, wTall + 9 * S, decBf, d_out, flag);
  } else {
    // --- fallback: serial per-expert path (fits in 138MB) ---
    for (int e = 0; e < NEXP; ++e) {
      transpose_cvt<<<dim3(HID / 32, HID / 32, 1), tb, 0, stream>>>(
          expW, (ushort_t*)wT, HID, HID, (size_t)e * HID * HID, flag, 0, 0);
      expert_gemm<<<dim3(N_TOK / 128, HID / 128, 1), 256, 0, stream>>>(
          hbuf, wT, 0, expBf, perm, cnt, e, s0g, mid);
    }
    transpose_cvt<<<dim3(HID / 32, HID / 32, 1), tb, 0, stream>>>(
        resW, (ushort_t*)wT, HID, HID, 0, flag, 0, 0);
    res_gemm<<<dim3(N_TOK / 128, HID / 128), 256, 0, stream>>>(hbuf, wT, resBf,
                                                               s1g, mid);
    transpose_cvt<<<dim3(IN_DIM / 32, HID / 32, 1), tb, 0, stream>>>(
        decW, (ushort_t*)wT, HID, IN_DIM, 0, flag, 0, 0);
    dec_gemm<<<dim3(N_TOK / 128, IN_DIM / 128), 256, 0, stream>>>(
        mid, wT, decBf, d_out, flag);
  }
}